// Round 6
// baseline (154.103 us; speedup 1.0000x reference)
//
#include <hip/hip_runtime.h>
#include <hip/hip_fp16.h>
#include <cmath>

// RestorationLoss = (1 - mean(SSIM(r_low, r_high))) + mean((r_low - r_high)^2)
// Separable 11x11 gaussian; 4 conv fields: mu1, mu2, S=conv(a^2+b^2), P=conv(ab).
// out = 1 + sum(d^2 - ssim_px)/N.
// R17 = R16 + persistent column-strip blocks (churn/latency round).
// R16 post-mortem: occupancy pinned at ~12 waves/CU (= 3 blocks) across
// static caps of 4/6/8 blocks -> extra residency headroom buys nothing;
// ~34us non-VALU time = per-block cold-start (900cy HBM under 3 waves/SIMD)
// + prologue/epilogue + drain/refill gaps, paid 6144x.
//  - grid 16x48 = 768 blocks = exactly 3/CU; each block chains NT=8 vertical
//    tiles over one 32-wide column strip; single hbuf, re-staged per tile.
//  - T14 async split at tile boundaries: next tile's batch-A loads (xP)
//    issue BEFORE phase-2 of current tile -> HBM latency hides under VALU.
//  - MSE window rl in [5,69) counts each global row exactly once (staging
//    overlap rows land at rl in [0,5) and [69,74) -> excluded).
//  - loadRow interior fast path (bx in [1,14] && rowOK): 10 straight float4
//    loads, no cndmask zero-fill; slow path only on edge blocks / OOB rows.
//  - #pragma unroll 1 on tile loop (avoid 8x code bloat / I$ pressure).
// Frozen: 32x64 tile, fp16-packed hbuf[74][33] uint2 (19.5 KB), packed-f32
// (v2f) conv math, MSE folded into phase-1, rcp ssim epilogue, 256 thr,
// launch_bounds(256,4), R9 load/conv pipeline shape.

#define HH 512
#define WW 512
#define TILE_H 64
#define TILE_W 32
#define NT (HH / TILE_H)                          // 8 chained tiles per block
#define HB (TILE_H + 10)                          // 74 staged rows
#define LDW 33                                    // padded row: 33 uint2
#define NPLANES 48
#define CT (WW / TILE_W)                          // 16
#define NBLOCKS (NPLANES * CT)                    // 768 = 3 per CU exactly

struct GW { float g[11]; };

typedef float v2f __attribute__((ext_vector_type(2)));

__device__ __forceinline__ unsigned pack2(float a, float b) {
    __half2 h = __floats2half2_rn(a, b);
    return __builtin_bit_cast(unsigned, h);
}
__device__ __forceinline__ v2f unpack2(unsigned u) {
    __half2 h = __builtin_bit_cast(__half2, u);
    float2 f = __half22float2(h);
    return (v2f){f.x, f.y};
}

__global__ __launch_bounds__(256, 4)
void ssim_main(const float* __restrict__ img1, const float* __restrict__ img2,
               float* __restrict__ partial, GW gw)
{
    __shared__ uint2 hbuf[HB][LDW];               // (mu1,mu2)|(S,P) fp16: 19536 B
    __shared__ float red[4];

    const int tid   = threadIdx.x;
    const int bx    = blockIdx.x;                 // column strip
    const int plane = blockIdx.y;
    const int col0  = bx * TILE_W;
    const float* p1 = img1 + (size_t)plane * (HH * WW);
    const float* p2 = img2 + (size_t)plane * (HH * WW);

    const int cg    = tid & 7;                    // col group: tile cols 4cg..4cg+3
    const int rs    = tid >> 3;                   // 0..31 row slot
    const int cbase = col0 + 4 * cg - 8;          // 20-float window, 16B aligned
    const bool interiorCol = (bx > 0) && (bx < CT - 1);  // all 5 vectors in-bounds

    float local = 0.f;                            // mse (phase 1) - ssim (phase 2)

    // 5 float4-pair loads; fast path for interior columns + in-bounds row.
    // OOB vectors (col OR row) become zeros == reference zero padding.
    auto loadRow = [&](int grow, float4* x1, float4* x2) {
        const bool rowOK = (grow >= 0) && (grow < HH);
        const int growc = min(max(grow, 0), HH - 1);      // addr always in-bounds
        const float* r1 = p1 + (size_t)growc * WW;
        const float* r2 = p2 + (size_t)growc * WW;
        if (rowOK && interiorCol) {
            #pragma unroll
            for (int v = 0; v < 5; ++v) {
                x1[v] = *reinterpret_cast<const float4*>(r1 + cbase + 4 * v);
                x2[v] = *reinterpret_cast<const float4*>(r2 + cbase + 4 * v);
            }
        } else {
            #pragma unroll
            for (int v = 0; v < 5; ++v) {
                const int c0 = cbase + 4 * v;
                if (rowOK && c0 >= 0 && c0 + 4 <= WW) {
                    x1[v] = *reinterpret_cast<const float4*>(r1 + c0);
                    x2[v] = *reinterpret_cast<const float4*>(r2 + c0);
                } else {
                    x1[v] = make_float4(0.f, 0.f, 0.f, 0.f);
                    x2[v] = make_float4(0.f, 0.f, 0.f, 0.f);
                }
            }
        }
    };

    // horizontal conv of one staged row -> packed fp16 hbuf[rl][col]
    // + MSE for tile rows (rl in [5,68]); staging-overlap rows excluded.
    auto convStore = [&](int rl, const float4* x1v, const float4* x2v) {
        const float* x1 = reinterpret_cast<const float*>(x1v);
        const float* x2 = reinterpret_cast<const float*>(x2v);
        if (rl >= 5 && rl < 69) {                 // this thread's 4 tile pixels
            #pragma unroll
            for (int i = 0; i < 4; ++i) {
                float d = x1[8 + i] - x2[8 + i];
                local += d * d;
            }
        }
        v2f acc01[4], acc23[4];
        #pragma unroll
        for (int i = 0; i < 4; ++i) {
            acc01[i] = (v2f){0.f, 0.f};
            acc23[i] = (v2f){0.f, 0.f};
        }
        #pragma unroll
        for (int e = 3; e <= 16; ++e) {           // out col i uses e = i+j+3
            float a  = x1[e], b = x2[e];
            v2f ab = (v2f){a, b};
            v2f t  = ab * ab;                     // pk_mul: (a^2, b^2)
            v2f vv = (v2f){t.x + t.y, a * b};     // (S-term, P-term)
            #pragma unroll
            for (int i = 0; i < 4; ++i) {
                int j = e - 3 - i;
                if (j >= 0 && j < 11) {
                    float w = gw.g[j];
                    v2f wv = (v2f){w, w};
                    acc01[i] += wv * ab;          // pk_fma
                    acc23[i] += wv * vv;          // pk_fma
                }
            }
        }
        #pragma unroll
        for (int i = 0; i < 4; ++i) {
            uint2 px;
            px.x = pack2(acc01[i].x, acc01[i].y);
            px.y = pack2(acc23[i].x, acc23[i].y);
            hbuf[rl][4 * cg + i] = px;            // 4 adjacent b64 (merge to b128)
        }
    };

    const bool third = (rs < 10);

    // ---- initial full staging of tile 0 (R9 pipeline) ----
    {
        float4 xA1[5], xA2[5], xB1[5], xB2[5];
        loadRow(-5 + rs, xA1, xA2);               // rows -5..26 (top zero-fill)
        loadRow(27 + rs, xB1, xB2);               // rows 27..58
        convStore(rs, xA1, xA2);                  // under B's load latency
        if (third) loadRow(59 + rs, xA1, xA2);    // rows 59..68
        convStore(rs + 32, xB1, xB2);
        if (third) convStore(rs + 64, xA1, xA2);
    }

    float4 xP1[5], xP2[5];                        // next-tile batch-A prefetch
    #pragma unroll 1
    for (int t = 0; t < NT; ++t) {
        const int row0 = t * TILE_H;
        __syncthreads();                          // staging of tile t complete

        if (t + 1 < NT)                           // T14: issue next tile's A loads
            loadRow(row0 + TILE_H - 5 + rs, xP1, xP2);

        // ---- Phase 2: vertical conv (18 b64 reads / 8 rows) + ssim ----
        {
            const int tx = tid & 31;              // pixel column
            const int rg = tid >> 5;              // 0..7 -> rows 8rg..8rg+7
            v2f res01[8], res23[8];
            #pragma unroll
            for (int p = 0; p < 8; ++p) {
                res01[p] = (v2f){0.f, 0.f};
                res23[p] = (v2f){0.f, 0.f};
            }
            #pragma unroll
            for (int j = 0; j < 18; ++j) {        // window rows rg*8 .. rg*8+17
                uint2 u = hbuf[rg * 8 + j][tx];
                v2f f01 = unpack2(u.x);           // (mu1, mu2)
                v2f f23 = unpack2(u.y);           // (S, P)
                #pragma unroll
                for (int p = 0; p < 8; ++p) {
                    int tt = j - p;
                    if (tt >= 0 && tt < 11) {
                        float w = gw.g[tt];
                        v2f wv = (v2f){w, w};
                        res01[p] += wv * f01;     // pk_fma
                        res23[p] += wv * f23;     // pk_fma
                    }
                }
            }
            const float C1c = 0.0001f, C2c = 0.0009f;
            #pragma unroll
            for (int p = 0; p < 8; ++p) {
                float mu1 = res01[p].x, mu2 = res01[p].y;
                float S   = res23[p].x, P   = res23[p].y;
                float m11 = mu1 * mu1, m22 = mu2 * mu2, m12 = mu1 * mu2;
                float num = (2.f * m12 + C1c) * (2.f * (P - m12) + C2c);
                float den = (m11 + m22 + C1c) * ((S - m11 - m22) + C2c);
                float inv = __builtin_amdgcn_rcpf(den);  // ~1ulp vs 2.3e-2 thr
                local -= num * inv;
            }
        }

        if (t + 1 < NT) {
            __syncthreads();                      // phase-2 reads done; reuse hbuf
            const int nrow0 = row0 + TILE_H;
            float4 xB1[5], xB2[5];
            loadRow(nrow0 + 27 + rs, xB1, xB2);   // issue B
            convStore(rs, xP1, xP2);              // A compute (loaded long ago)
            if (third) loadRow(nrow0 + 59 + rs, xP1, xP2);   // issue C
            convStore(rs + 32, xB1, xB2);         // B compute under C latency
            if (third) convStore(rs + 64, xP1, xP2);
        }
    }

    // ---- block reduce ----
    #pragma unroll
    for (int off = 32; off > 0; off >>= 1) local += __shfl_down(local, off);
    if ((tid & 63) == 0) red[tid >> 6] = local;
    __syncthreads();
    if (tid == 0)
        partial[plane * CT + bx] = (red[0] + red[1]) + (red[2] + red[3]);
}

__global__ __launch_bounds__(256)
void ssim_finish(const float* __restrict__ partial, float* __restrict__ out)
{
    __shared__ float red[256];
    float s = 0.f;
    #pragma unroll
    for (int i = 0; i < NBLOCKS / 256; ++i)       // 3 independent loads
        s += partial[i * 256 + threadIdx.x];
    red[threadIdx.x] = s;
    __syncthreads();
    for (int step = 128; step > 0; step >>= 1) {
        if ((int)threadIdx.x < step) red[threadIdx.x] += red[threadIdx.x + step];
        __syncthreads();
    }
    if (threadIdx.x == 0)
        out[0] = 1.0f + red[0] * (1.0f / 12582912.0f);
}

extern "C" void kernel_launch(void* const* d_in, const int* in_sizes, int n_in,
                              void* d_out, int out_size, void* d_ws, size_t ws_size,
                              hipStream_t stream)
{
    const float* r_low  = (const float*)d_in[0];
    const float* r_high = (const float*)d_in[1];
    float* out     = (float*)d_out;
    float* partial = (float*)d_ws;                       // 768 floats

    GW gw;                                               // gaussian -> SGPRs
    {
        float s = 0.f;
        for (int i = 0; i < 11; ++i) {
            float c = (float)(i - 5);
            gw.g[i] = expf(-(c * c) / 4.5f);             // 2*sigma^2 = 4.5
            s += gw.g[i];
        }
        for (int i = 0; i < 11; ++i) gw.g[i] /= s;
    }

    dim3 grid(CT, NPLANES);
    ssim_main<<<grid, dim3(256), 0, stream>>>(r_low, r_high, partial, gw);
    ssim_finish<<<1, dim3(256), 0, stream>>>(partial, out);
}

// Round 7
// 150.713 us; speedup vs baseline: 1.0225x; 1.0225x over previous
//
#include <hip/hip_runtime.h>
#include <cmath>

// RestorationLoss = (1 - mean(SSIM(r_low, r_high))) + mean((r_low - r_high)^2)
// Separable 11x11 gaussian; 4 conv fields: mu1, mu2, S=conv(a^2+b^2), P=conv(ab).
// out = 1 + sum(d^2 - ssim_px)/N.
// R18 = R17 + fp32 staging + VGPR headroom (per-wave stall round).
// R17 post-mortem: 3 waves/SIMD x ~20% per-wave issue rate = 52% VALUBusy;
// waves stall ~80% on ds_read->cvt->fma chains under a VGPR=64 budget.
// Residency is pinned at 3 blocks/CU BY CONSTRUCTION now (persistent grid),
// so fp16 staging buys nothing (53 KB LDS/block available) and its 8+72
// cvts/thread/tile are pure critical-path overhead:
//  - hbuf: uint2 fp16 -> float4 fp32 (39.1 KB): no pack/unpack cvts, LDS
//    chain is ds_read_b128 -> pk_fma directly.
//  - launch_bounds(256,3): VGPR cap ~170 (was 64) -> compiler can hoist
//    phase-2 LDS reads / deepen ILP. Spill tripwire: WRITE_SIZE must stay
//    ~25 KB; if MB-scale, revert to (256,4).
// Frozen: persistent 32-col strips (768 blocks = 3/CU), NT=8 chained tiles,
// T14 cross-tile prefetch, packed-f32 (v2f) conv math, MSE folded into
// phase-1 (rl in [5,69) counts each row once), interior-col fast path,
// rcp ssim epilogue, 256 thr, R9 pipeline shape, unroll-1 tile loop.

#define HH 512
#define WW 512
#define TILE_H 64
#define TILE_W 32
#define NT (HH / TILE_H)                          // 8 chained tiles per block
#define HB (TILE_H + 10)                          // 74 staged rows
#define LDW 33                                    // padded row: 33 float4s
#define NPLANES 48
#define CT (WW / TILE_W)                          // 16
#define NBLOCKS (NPLANES * CT)                    // 768 = 3 per CU exactly

struct GW { float g[11]; };

typedef float v2f __attribute__((ext_vector_type(2)));

__global__ __launch_bounds__(256, 3)
void ssim_main(const float* __restrict__ img1, const float* __restrict__ img2,
               float* __restrict__ partial, GW gw)
{
    __shared__ float4 hbuf[HB][LDW];              // (mu1,mu2,S,P) fp32: 39072 B
    __shared__ float red[4];

    const int tid   = threadIdx.x;
    const int bx    = blockIdx.x;                 // column strip
    const int plane = blockIdx.y;
    const int col0  = bx * TILE_W;
    const float* p1 = img1 + (size_t)plane * (HH * WW);
    const float* p2 = img2 + (size_t)plane * (HH * WW);

    const int cg    = tid & 7;                    // col group: tile cols 4cg..4cg+3
    const int rs    = tid >> 3;                   // 0..31 row slot
    const int cbase = col0 + 4 * cg - 8;          // 20-float window, 16B aligned
    const bool interiorCol = (bx > 0) && (bx < CT - 1);  // all 5 vectors in-bounds

    float local = 0.f;                            // mse (phase 1) - ssim (phase 2)

    // 5 float4-pair loads; fast path for interior columns + in-bounds row.
    // OOB vectors (col OR row) become zeros == reference zero padding.
    auto loadRow = [&](int grow, float4* x1, float4* x2) {
        const bool rowOK = (grow >= 0) && (grow < HH);
        const int growc = min(max(grow, 0), HH - 1);      // addr always in-bounds
        const float* r1 = p1 + (size_t)growc * WW;
        const float* r2 = p2 + (size_t)growc * WW;
        if (rowOK && interiorCol) {
            #pragma unroll
            for (int v = 0; v < 5; ++v) {
                x1[v] = *reinterpret_cast<const float4*>(r1 + cbase + 4 * v);
                x2[v] = *reinterpret_cast<const float4*>(r2 + cbase + 4 * v);
            }
        } else {
            #pragma unroll
            for (int v = 0; v < 5; ++v) {
                const int c0 = cbase + 4 * v;
                if (rowOK && c0 >= 0 && c0 + 4 <= WW) {
                    x1[v] = *reinterpret_cast<const float4*>(r1 + c0);
                    x2[v] = *reinterpret_cast<const float4*>(r2 + c0);
                } else {
                    x1[v] = make_float4(0.f, 0.f, 0.f, 0.f);
                    x2[v] = make_float4(0.f, 0.f, 0.f, 0.f);
                }
            }
        }
    };

    // horizontal conv of one staged row -> fp32 hbuf[rl][col]
    // + MSE for tile rows (rl in [5,68]); staging-overlap rows excluded.
    auto convStore = [&](int rl, const float4* x1v, const float4* x2v) {
        const float* x1 = reinterpret_cast<const float*>(x1v);
        const float* x2 = reinterpret_cast<const float*>(x2v);
        if (rl >= 5 && rl < 69) {                 // this thread's 4 tile pixels
            #pragma unroll
            for (int i = 0; i < 4; ++i) {
                float d = x1[8 + i] - x2[8 + i];
                local += d * d;
            }
        }
        v2f acc01[4], acc23[4];
        #pragma unroll
        for (int i = 0; i < 4; ++i) {
            acc01[i] = (v2f){0.f, 0.f};
            acc23[i] = (v2f){0.f, 0.f};
        }
        #pragma unroll
        for (int e = 3; e <= 16; ++e) {           // out col i uses e = i+j+3
            float a  = x1[e], b = x2[e];
            v2f ab = (v2f){a, b};
            v2f t  = ab * ab;                     // pk_mul: (a^2, b^2)
            v2f vv = (v2f){t.x + t.y, a * b};     // (S-term, P-term)
            #pragma unroll
            for (int i = 0; i < 4; ++i) {
                int j = e - 3 - i;
                if (j >= 0 && j < 11) {
                    float w = gw.g[j];
                    v2f wv = (v2f){w, w};
                    acc01[i] += wv * ab;          // pk_fma
                    acc23[i] += wv * vv;          // pk_fma
                }
            }
        }
        #pragma unroll
        for (int i = 0; i < 4; ++i)
            hbuf[rl][4 * cg + i] = make_float4(acc01[i].x, acc01[i].y,
                                               acc23[i].x, acc23[i].y);
    };

    const bool third = (rs < 10);

    // ---- initial full staging of tile 0 (R9 pipeline) ----
    {
        float4 xA1[5], xA2[5], xB1[5], xB2[5];
        loadRow(-5 + rs, xA1, xA2);               // rows -5..26 (top zero-fill)
        loadRow(27 + rs, xB1, xB2);               // rows 27..58
        convStore(rs, xA1, xA2);                  // under B's load latency
        if (third) loadRow(59 + rs, xA1, xA2);    // rows 59..68
        convStore(rs + 32, xB1, xB2);
        if (third) convStore(rs + 64, xA1, xA2);
    }

    float4 xP1[5], xP2[5];                        // next-tile batch-A prefetch
    #pragma unroll 1
    for (int t = 0; t < NT; ++t) {
        const int row0 = t * TILE_H;
        __syncthreads();                          // staging of tile t complete

        if (t + 1 < NT)                           // T14: issue next tile's A loads
            loadRow(row0 + TILE_H - 5 + rs, xP1, xP2);

        // ---- Phase 2: vertical conv (18 b128 reads / 8 rows) + ssim ----
        {
            const int tx = tid & 31;              // pixel column
            const int rg = tid >> 5;              // 0..7 -> rows 8rg..8rg+7
            v2f res01[8], res23[8];
            #pragma unroll
            for (int p = 0; p < 8; ++p) {
                res01[p] = (v2f){0.f, 0.f};
                res23[p] = (v2f){0.f, 0.f};
            }
            #pragma unroll
            for (int j = 0; j < 18; ++j) {        // window rows rg*8 .. rg*8+17
                float4 u = hbuf[rg * 8 + j][tx];
                v2f f01 = (v2f){u.x, u.y};        // (mu1, mu2)
                v2f f23 = (v2f){u.z, u.w};        // (S, P)
                #pragma unroll
                for (int p = 0; p < 8; ++p) {
                    int tt = j - p;
                    if (tt >= 0 && tt < 11) {
                        float w = gw.g[tt];
                        v2f wv = (v2f){w, w};
                        res01[p] += wv * f01;     // pk_fma
                        res23[p] += wv * f23;     // pk_fma
                    }
                }
            }
            const float C1c = 0.0001f, C2c = 0.0009f;
            #pragma unroll
            for (int p = 0; p < 8; ++p) {
                float mu1 = res01[p].x, mu2 = res01[p].y;
                float S   = res23[p].x, P   = res23[p].y;
                float m11 = mu1 * mu1, m22 = mu2 * mu2, m12 = mu1 * mu2;
                float num = (2.f * m12 + C1c) * (2.f * (P - m12) + C2c);
                float den = (m11 + m22 + C1c) * ((S - m11 - m22) + C2c);
                float inv = __builtin_amdgcn_rcpf(den);  // ~1ulp vs 2.3e-2 thr
                local -= num * inv;
            }
        }

        if (t + 1 < NT) {
            __syncthreads();                      // phase-2 reads done; reuse hbuf
            const int nrow0 = row0 + TILE_H;
            float4 xB1[5], xB2[5];
            loadRow(nrow0 + 27 + rs, xB1, xB2);   // issue B
            convStore(rs, xP1, xP2);              // A compute (loaded long ago)
            if (third) loadRow(nrow0 + 59 + rs, xP1, xP2);   // issue C
            convStore(rs + 32, xB1, xB2);         // B compute under C latency
            if (third) convStore(rs + 64, xP1, xP2);
        }
    }

    // ---- block reduce ----
    #pragma unroll
    for (int off = 32; off > 0; off >>= 1) local += __shfl_down(local, off);
    if ((tid & 63) == 0) red[tid >> 6] = local;
    __syncthreads();
    if (tid == 0)
        partial[plane * CT + bx] = (red[0] + red[1]) + (red[2] + red[3]);
}

__global__ __launch_bounds__(256)
void ssim_finish(const float* __restrict__ partial, float* __restrict__ out)
{
    __shared__ float red[256];
    float s = 0.f;
    #pragma unroll
    for (int i = 0; i < NBLOCKS / 256; ++i)       // 3 independent loads
        s += partial[i * 256 + threadIdx.x];
    red[threadIdx.x] = s;
    __syncthreads();
    for (int step = 128; step > 0; step >>= 1) {
        if ((int)threadIdx.x < step) red[threadIdx.x] += red[threadIdx.x + step];
        __syncthreads();
    }
    if (threadIdx.x == 0)
        out[0] = 1.0f + red[0] * (1.0f / 12582912.0f);
}

extern "C" void kernel_launch(void* const* d_in, const int* in_sizes, int n_in,
                              void* d_out, int out_size, void* d_ws, size_t ws_size,
                              hipStream_t stream)
{
    const float* r_low  = (const float*)d_in[0];
    const float* r_high = (const float*)d_in[1];
    float* out     = (float*)d_out;
    float* partial = (float*)d_ws;                       // 768 floats

    GW gw;                                               // gaussian -> SGPRs
    {
        float s = 0.f;
        for (int i = 0; i < 11; ++i) {
            float c = (float)(i - 5);
            gw.g[i] = expf(-(c * c) / 4.5f);             // 2*sigma^2 = 4.5
            s += gw.g[i];
        }
        for (int i = 0; i < 11; ++i) gw.g[i] /= s;
    }

    dim3 grid(CT, NPLANES);
    ssim_main<<<grid, dim3(256), 0, stream>>>(r_low, r_high, partial, gw);
    ssim_finish<<<1, dim3(256), 0, stream>>>(partial, out);
}